// Round 1
// 140.955 us; speedup vs baseline: 1.0741x; 1.0741x over previous
//
#include <hip/hip_runtime.h>
#include <math.h>

// DenseGATv2Layer: N=4096, IN=128, HEADS=4, OUT_DIM=64.
// R11: eliminate the accp round-trip (32 MB write + 32 MB read + extra
// dispatch). j-split moves from cross-block (jsplit=8 + reduce_part) to
// intra-block: block = 32 rows x 1 head, 8 waves = 8 j-slices of 512 cols
// (inner loop identical to R8/R10). Cross-wave combine is __syncthreads +
// LDS [8][32][64] tree -- workgroup scope only, so R9's threadfence/L2
// disaster does not apply. Grid 512x512 = exactly 2 blocks/CU (130 KB LDS),
// same 4 waves/SIMD as R10, zero dispatch tail.
// Also: exp2(lrelu(v)-8) refactored to exp2(max(siAa+sj, fma(0.2,sj,siAb)))
// with siAa=si-8, siAb=0.2si-8 hoisted (kills per-element mul+sub).
//   D1 prep_k    : unchanged from R10.
//   D2 gat_fused : MFMA aggregation + in-block normalize + direct out write.

#define N 4096
#define IN_DIM 128
#define HEADS 4
#define OUT_DIM 64
#define HD 256
#define LOG2E 1.4426950408889634f
#define PSHIFT 8.0f

typedef _Float16 f16x8 __attribute__((ext_vector_type(8)));
typedef __fp16 fp16x2 __attribute__((ext_vector_type(2)));
typedef float f32x4 __attribute__((ext_vector_type(4)));

union F16x8u { fp16x2 h2[4]; f16x8 v; };

// ws layout (bytes)
#define WS_HB_OFF    0u          // _Float16 hb[2048][512]      (2 MB) frag-linear
#define WS_SSRC_OFF  2097152u    // float s_src[N][4]   (scaled by log2e)
#define WS_SDT_OFF   2162688u    // float s_dst_t[4][N] (scaled)
#define WS_BITT_OFF  2228224u    // uint bits_t[64][128][64]    (2 MB)
#define WS_HSUMP_OFF 4325376u    // float hsum_part[512][256]   (512 KB)

__device__ __forceinline__ unsigned pack_bytes(unsigned v) {
  return (v & 1u) | ((v >> 7) & 2u) | ((v >> 14) & 4u) | ((v >> 21) & 8u);
}

// ---------------- D1: fused mask-pack + h-compute (unchanged) ----------------
__global__ __launch_bounds__(256) void prep_k(const void* __restrict__ mraw,
                                              unsigned* __restrict__ bits_t,
                                              const float* __restrict__ x,
                                              const float* __restrict__ W,
                                              const float* __restrict__ a_src,
                                              const float* __restrict__ a_dst,
                                              _Float16* __restrict__ hb,
                                              float* __restrict__ s_src,
                                              float* __restrict__ s_dst_t,
                                              float* __restrict__ hsum_part) {
  if (blockIdx.x < 2048) {
    // ---- mask pack: detect format from first 4KB (L2 broadcast) ----
    __shared__ int s_flag;
    if (threadIdx.x == 0) s_flag = 0;
    __syncthreads();
    const unsigned* mw = (const unsigned*)mraw;
    int bad = 0, g = 0;
    for (int i = threadIdx.x; i < 1024; i += 256) {
      unsigned v = mw[i];
      if (v & 0xFEFEFEFEu) bad = 1;
      if (v > 1u) g = 1;
    }
    if (bad || g) atomicOr(&s_flag, (bad ? 1 : 0) | (g ? 2 : 0));
    __syncthreads();
    const bool byte_fmt = ((s_flag & 1) == 0) && ((s_flag & 2) != 0);

    int w = blockIdx.x * 256 + threadIdx.x;  // word idx, N*N/32 total
    unsigned ob = 0u;
    if (byte_fmt) {
      const uint4* p = (const uint4*)((const unsigned char*)mraw + (size_t)w * 32u);
      uint4 a = p[0], b = p[1];
      ob  =  pack_bytes(a.x)        | (pack_bytes(a.y) << 4)  | (pack_bytes(a.z) << 8)  | (pack_bytes(a.w) << 12);
      ob |= (pack_bytes(b.x) << 16) | (pack_bytes(b.y) << 20) | (pack_bytes(b.z) << 24) | (pack_bytes(b.w) << 28);
    } else {
      const uint4* p = (const uint4*)((const unsigned*)mraw + (size_t)w * 32u);
#pragma unroll
      for (int k = 0; k < 8; ++k) {
        uint4 v = p[k];
        ob |= (v.x ? 1u : 0u) << (4 * k);
        ob |= (v.y ? 1u : 0u) << (4 * k + 1);
        ob |= (v.z ? 1u : 0u) << (4 * k + 2);
        ob |= (v.w ? 1u : 0u) << (4 * k + 3);
      }
    }
    const int row = w >> 7, jc = w & 127;
    bits_t[((size_t)(row >> 6) * 128 + jc) * 64 + (row & 63)] = ob;
  } else {
    // ---- h = x@W (8 rows), LDS-staged x, frag-linear hb, s vectors, hsum ----
    __shared__ float xs[8][IN_DIM];  // 4 KB
    const int blk = blockIdx.x - 2048;
    const int i0 = blk * 8;
    const int c = threadIdx.x;

    ((float4*)&xs[0][0])[c] = ((const float4*)(x + (size_t)i0 * IN_DIM))[c];
    __syncthreads();

    float acc[8];
#pragma unroll
    for (int r = 0; r < 8; ++r) acc[r] = 0.f;

    for (int kk = 0; kk < IN_DIM / 4; ++kk) {
      const int k = kk * 4;
      float w0 = W[(size_t)(k + 0) * HD + c];
      float w1 = W[(size_t)(k + 1) * HD + c];
      float w2 = W[(size_t)(k + 2) * HD + c];
      float w3 = W[(size_t)(k + 3) * HD + c];
#pragma unroll
      for (int r = 0; r < 8; ++r) {
        float4 xv = *(const float4*)(&xs[r][k]);  // wave-uniform LDS broadcast
        acc[r] = fmaf(xv.x, w0, fmaf(xv.y, w1, fmaf(xv.z, w2, fmaf(xv.w, w3, acc[r]))));
      }
    }

    // frag-linear store: unit=(head, chunk=i0>>5, nt); elem(lane', t=r)
    {
      const int head = c >> 6, nt = (c >> 4) & 3, m15 = c & 15;
      const int unit = (head * 128 + (i0 >> 5)) * 4 + nt;
      const int lanep = ((i0 & 31) >> 3) * 16 + m15;
      f16x8 v;
#pragma unroll
      for (int r = 0; r < 8; ++r) v[r] = (_Float16)acc[r];
      *(f16x8*)(hb + (size_t)unit * 512 + lanep * 8) = v;
    }

    // per-block column sums (plain store, no atomics) for empty-row fallback
    {
      float loc = 0.f;
#pragma unroll
      for (int r = 0; r < 8; ++r) loc += acc[r];
      hsum_part[(size_t)blk * HD + c] = loc;
    }

    const int hw = c >> 6, lane = c & 63;
    const float as = a_src[lane], ad = a_dst[lane];
#pragma unroll
    for (int r = 0; r < 8; ++r) {
      float vs = acc[r] * as, vd = acc[r] * ad;
#pragma unroll
      for (int off = 1; off < 64; off <<= 1) {
        vs += __shfl_xor(vs, off);
        vd += __shfl_xor(vd, off);
      }
      if (lane == 0) {
        s_src[(size_t)(i0 + r) * HEADS + hw] = vs * LOG2E;
        s_dst_t[(size_t)hw * N + (i0 + r)] = vd * LOG2E;
      }
    }
  }
}

// ---------------- D2: MFMA aggregation + in-block LDS reduce + normalize ----
// block = 32 rows x 1 head; 8 waves = 8 j-slices of 512 columns each.
// grid mapping: head = blockIdx>>7 (rb inner) so the 4 head-blocks of the
// same rows land on the SAME XCD (128 === 0 mod 8) -> bits_t fetched once/XCD.
__global__ __launch_bounds__(512, 4) void gat_fused(const _Float16* __restrict__ hb,
                                                    const float* __restrict__ s_src,
                                                    const float* __restrict__ s_dst_t,
                                                    const unsigned* __restrict__ bits_t,
                                                    const float* __restrict__ hsum_part,
                                                    float4* __restrict__ out) {
  __shared__ float red[8][32][64];  // 64 KB: per-wave partial out tiles
  __shared__ float lred[8][32];     // 1 KB : per-wave partial row sums

  const int tid = threadIdx.x;
  const int w = tid >> 6;          // j-slice index (wave)
  const int lane = tid & 63;
  const int m15 = lane & 15;
  const int quad = lane >> 4;
  const int head = blockIdx.x >> 7;
  const int rb = blockIdx.x & 127;
  const int i0 = rb * 32;
  const int rA = i0 + m15;
  const int rB = rA + 16;

  const float siA = s_src[(size_t)rA * HEADS + head];
  const float siB = s_src[(size_t)rB * HEADS + head];
  // exp2(lrelu(v)-8) = exp2(max(v-8, 0.2v-8)); hoist the si parts.
  const float siAa = siA - PSHIFT, siAb = 0.2f * siA - PSHIFT;
  const float siBa = siB - PSHIFT, siBb = 0.2f * siB - PSHIFT;

  // bits_t[[row>>6]][jc][row&63]; rows i0..i0+31 -> row>>6 = rb>>1 const.
  const unsigned* mt = bits_t + ((size_t)(rb >> 1) * 128 + w * 16) * 64 + (i0 & 32) + m15;
  const float* sjb = s_dst_t + (size_t)head * N + w * 512 + quad * 8;
  const _Float16* hbp = hb + ((size_t)(head * 128 + w * 16) * 4) * 512 + lane * 8;

  f32x4 accA0 = {0.f, 0.f, 0.f, 0.f}, accA1 = accA0, accA2 = accA0, accA3 = accA0;
  f32x4 accB0 = accA0, accB1 = accA0, accB2 = accA0, accB3 = accA0;
  float lA = 0.f, lB = 0.f;

  const int shq = quad * 8;

  for (int c = 0; c < 16; ++c) {
    const unsigned mwA = mt[c * 64];
    const unsigned mwB = mt[c * 64 + 16];
    const float4 sa = *(const float4*)(sjb + c * 32);
    const float4 sb = *(const float4*)(sjb + c * 32 + 4);

    const f16x8 b0 = *(const f16x8*)(hbp + (size_t)(c * 4 + 0) * 512);
    const f16x8 b1 = *(const f16x8*)(hbp + (size_t)(c * 4 + 1) * 512);
    const f16x8 b2 = *(const f16x8*)(hbp + (size_t)(c * 4 + 2) * 512);
    const f16x8 b3 = *(const f16x8*)(hbp + (size_t)(c * 4 + 3) * 512);

    const unsigned wA = mwA >> shq;
    const unsigned wB = mwB >> shq;
    const float sjs[8] = {sa.x, sa.y, sa.z, sa.w, sb.x, sb.y, sb.z, sb.w};

    F16x8u uA, uB;
#pragma unroll
    for (int t2 = 0; t2 < 4; ++t2) {
      float pA[2], pB[2];
#pragma unroll
      for (int q = 0; q < 2; ++q) {
        const int t = t2 * 2 + q;
        const float sj = sjs[t];
        const float mA = fmaxf(siAa + sj, fmaf(0.2f, sj, siAb));
        const float mB = fmaxf(siBa + sj, fmaf(0.2f, sj, siBb));
        const float xA = (((wA >> t) & 1u) ? mA : -1.0e38f);
        const float xB = (((wB >> t) & 1u) ? mB : -1.0e38f);
        pA[q] = __builtin_amdgcn_exp2f(xA);
        pB[q] = __builtin_amdgcn_exp2f(xB);
        lA += pA[q];
        lB += pB[q];
      }
      uA.h2[t2] = __builtin_amdgcn_cvt_pkrtz(pA[0], pA[1]);
      uB.h2[t2] = __builtin_amdgcn_cvt_pkrtz(pB[0], pB[1]);
    }

    accA0 = __builtin_amdgcn_mfma_f32_16x16x32_f16(uA.v, b0, accA0, 0, 0, 0);
    accA1 = __builtin_amdgcn_mfma_f32_16x16x32_f16(uA.v, b1, accA1, 0, 0, 0);
    accA2 = __builtin_amdgcn_mfma_f32_16x16x32_f16(uA.v, b2, accA2, 0, 0, 0);
    accA3 = __builtin_amdgcn_mfma_f32_16x16x32_f16(uA.v, b3, accA3, 0, 0, 0);
    accB0 = __builtin_amdgcn_mfma_f32_16x16x32_f16(uB.v, b0, accB0, 0, 0, 0);
    accB1 = __builtin_amdgcn_mfma_f32_16x16x32_f16(uB.v, b1, accB1, 0, 0, 0);
    accB2 = __builtin_amdgcn_mfma_f32_16x16x32_f16(uB.v, b2, accB2, 0, 0, 0);
    accB3 = __builtin_amdgcn_mfma_f32_16x16x32_f16(uB.v, b3, accB3, 0, 0, 0);
  }

  // per-wave row sums (sum over quads = j-subgroups)
  lA += __shfl_xor(lA, 16); lA += __shfl_xor(lA, 32);
  lB += __shfl_xor(lB, 16); lB += __shfl_xor(lB, 32);
  if (quad == 0) {
    lred[w][m15] = lA;
    lred[w][16 + m15] = lB;
  }

  // stash per-wave partial tiles: row = quad*4+reg (+16 for B), col = m15+16u
#pragma unroll
  for (int reg = 0; reg < 4; ++reg) {
    const int ra = quad * 4 + reg;
    red[w][ra][m15 +  0] = accA0[reg];
    red[w][ra][m15 + 16] = accA1[reg];
    red[w][ra][m15 + 32] = accA2[reg];
    red[w][ra][m15 + 48] = accA3[reg];
    red[w][16 + ra][m15 +  0] = accB0[reg];
    red[w][16 + ra][m15 + 16] = accB1[reg];
    red[w][16 + ra][m15 + 32] = accB2[reg];
    red[w][16 + ra][m15 + 48] = accB3[reg];
  }
  __syncthreads();

  // combine 8 j-slices + normalize + write out. 512 thr = 32 rows x 16 col4.
  const int row = tid >> 4;
  const int c4 = tid & 15;
  float4 o = {0.f, 0.f, 0.f, 0.f};
  float lt = 0.f;
#pragma unroll
  for (int k = 0; k < 8; ++k) {
    const float4 v = *(const float4*)&red[k][row][c4 * 4];
    o.x += v.x; o.y += v.y; o.z += v.z; o.w += v.w;
    lt += lred[k][row];
  }
  if (lt == 0.f) {
    // empty row -> exact uniform 1/N: sum h over all j (512 block slices)
    float4 hs = {0.f, 0.f, 0.f, 0.f};
    for (int b = 0; b < 512; ++b) {
      float4 t4 = ((const float4*)hsum_part)[(size_t)b * 64 + head * 16 + c4];
      hs.x += t4.x; hs.y += t4.y; hs.z += t4.z; hs.w += t4.w;
    }
    const float cst = 1.0f / (float)N;
    o.x = hs.x * cst; o.y = hs.y * cst; o.z = hs.z * cst; o.w = hs.w * cst;
  } else {
    const float inv = 1.0f / lt;
    o.x *= inv; o.y *= inv; o.z *= inv; o.w *= inv;
  }
  out[(size_t)(i0 + row) * 64 + head * 16 + c4] = o;
}

extern "C" void kernel_launch(void* const* d_in, const int* in_sizes, int n_in,
                              void* d_out, int out_size, void* d_ws, size_t ws_size,
                              hipStream_t stream) {
  (void)in_sizes; (void)n_in; (void)out_size; (void)ws_size;
  const float* x = (const float*)d_in[0];
  const void* mask = d_in[1];
  const float* W = (const float*)d_in[2];
  const float* a_src = (const float*)d_in[3];
  const float* a_dst = (const float*)d_in[4];
  float* out = (float*)d_out;

  char* ws = (char*)d_ws;
  _Float16* hb = (_Float16*)(ws + WS_HB_OFF);
  float* s_src = (float*)(ws + WS_SSRC_OFF);
  float* s_dst_t = (float*)(ws + WS_SDT_OFF);
  unsigned* bits_t = (unsigned*)(ws + WS_BITT_OFF);
  float* hsum_part = (float*)(ws + WS_HSUMP_OFF);

  prep_k<<<2048 + N / 8, 256, 0, stream>>>(mask, bits_t, x, W, a_src, a_dst,
                                           hb, s_src, s_dst_t, hsum_part);
  gat_fused<<<512, 512, 0, stream>>>(hb, s_src, s_dst_t, bits_t, hsum_part,
                                     (float4*)out);
}

// Round 2
// 140.237 us; speedup vs baseline: 1.0796x; 1.0051x over previous
//
#include <hip/hip_runtime.h>
#include <math.h>

// DenseGATv2Layer: N=4096, IN=128, HEADS=4, OUT_DIM=64.
// R12: shrink gat_fused's two real costs (VALU chain + L2 re-reads).
//  - Block = 64 rows x 1 head, 1024 thr = 16 waves = 2 row-groups x 8 j-slices.
//    The two row-group waves of a j-slice stream IDENTICAL hb/sjb data ->
//    L1-shared, halving L2 hb traffic (256 MB -> 128 MB). Grid 256 = exactly
//    1 block/CU (141 KB LDS), still 4 waves/SIMD, zero tail.
//  - Row-sum l computed via MFMA with ones-B operand (accL): removes the 16
//    serial fp adds per chunk (VALU + dependency chain) for +2 MFMA on the
//    under-used matrix pipe; also deletes the shfl l-epilogue. l now sums the
//    exact f16 p values the numerator MFMA consumes.
//  - red[][][] padded to 68 floats/row: 4-row stride == 16 banks -> uniform
//    2-way (free), rows 16B-aligned for float4 LDS access.
//   D1 prep_k    : unchanged.
//   D2 gat_fused : MFMA aggregation + in-block reduce + normalize + out.

#define N 4096
#define IN_DIM 128
#define HEADS 4
#define OUT_DIM 64
#define HD 256
#define LOG2E 1.4426950408889634f
#define PSHIFT 8.0f

typedef _Float16 f16x8 __attribute__((ext_vector_type(8)));
typedef __fp16 fp16x2 __attribute__((ext_vector_type(2)));
typedef float f32x4 __attribute__((ext_vector_type(4)));

union F16x8u { fp16x2 h2[4]; f16x8 v; };

// ws layout (bytes)
#define WS_HB_OFF    0u          // _Float16 hb[2048][512]      (2 MB) frag-linear
#define WS_SSRC_OFF  2097152u    // float s_src[N][4]   (scaled by log2e)
#define WS_SDT_OFF   2162688u    // float s_dst_t[4][N] (scaled)
#define WS_BITT_OFF  2228224u    // uint bits_t[64][128][64]    (2 MB)
#define WS_HSUMP_OFF 4325376u    // float hsum_part[512][256]   (512 KB)

__device__ __forceinline__ unsigned pack_bytes(unsigned v) {
  return (v & 1u) | ((v >> 7) & 2u) | ((v >> 14) & 4u) | ((v >> 21) & 8u);
}

// ---------------- D1: fused mask-pack + h-compute (unchanged) ----------------
__global__ __launch_bounds__(256) void prep_k(const void* __restrict__ mraw,
                                              unsigned* __restrict__ bits_t,
                                              const float* __restrict__ x,
                                              const float* __restrict__ W,
                                              const float* __restrict__ a_src,
                                              const float* __restrict__ a_dst,
                                              _Float16* __restrict__ hb,
                                              float* __restrict__ s_src,
                                              float* __restrict__ s_dst_t,
                                              float* __restrict__ hsum_part) {
  if (blockIdx.x < 2048) {
    // ---- mask pack: detect format from first 4KB (L2 broadcast) ----
    __shared__ int s_flag;
    if (threadIdx.x == 0) s_flag = 0;
    __syncthreads();
    const unsigned* mw = (const unsigned*)mraw;
    int bad = 0, g = 0;
    for (int i = threadIdx.x; i < 1024; i += 256) {
      unsigned v = mw[i];
      if (v & 0xFEFEFEFEu) bad = 1;
      if (v > 1u) g = 1;
    }
    if (bad || g) atomicOr(&s_flag, (bad ? 1 : 0) | (g ? 2 : 0));
    __syncthreads();
    const bool byte_fmt = ((s_flag & 1) == 0) && ((s_flag & 2) != 0);

    int w = blockIdx.x * 256 + threadIdx.x;  // word idx, N*N/32 total
    unsigned ob = 0u;
    if (byte_fmt) {
      const uint4* p = (const uint4*)((const unsigned char*)mraw + (size_t)w * 32u);
      uint4 a = p[0], b = p[1];
      ob  =  pack_bytes(a.x)        | (pack_bytes(a.y) << 4)  | (pack_bytes(a.z) << 8)  | (pack_bytes(a.w) << 12);
      ob |= (pack_bytes(b.x) << 16) | (pack_bytes(b.y) << 20) | (pack_bytes(b.z) << 24) | (pack_bytes(b.w) << 28);
    } else {
      const uint4* p = (const uint4*)((const unsigned*)mraw + (size_t)w * 32u);
#pragma unroll
      for (int k = 0; k < 8; ++k) {
        uint4 v = p[k];
        ob |= (v.x ? 1u : 0u) << (4 * k);
        ob |= (v.y ? 1u : 0u) << (4 * k + 1);
        ob |= (v.z ? 1u : 0u) << (4 * k + 2);
        ob |= (v.w ? 1u : 0u) << (4 * k + 3);
      }
    }
    const int row = w >> 7, jc = w & 127;
    bits_t[((size_t)(row >> 6) * 128 + jc) * 64 + (row & 63)] = ob;
  } else {
    // ---- h = x@W (8 rows), LDS-staged x, frag-linear hb, s vectors, hsum ----
    __shared__ float xs[8][IN_DIM];  // 4 KB
    const int blk = blockIdx.x - 2048;
    const int i0 = blk * 8;
    const int c = threadIdx.x;

    ((float4*)&xs[0][0])[c] = ((const float4*)(x + (size_t)i0 * IN_DIM))[c];
    __syncthreads();

    float acc[8];
#pragma unroll
    for (int r = 0; r < 8; ++r) acc[r] = 0.f;

    for (int kk = 0; kk < IN_DIM / 4; ++kk) {
      const int k = kk * 4;
      float w0 = W[(size_t)(k + 0) * HD + c];
      float w1 = W[(size_t)(k + 1) * HD + c];
      float w2 = W[(size_t)(k + 2) * HD + c];
      float w3 = W[(size_t)(k + 3) * HD + c];
#pragma unroll
      for (int r = 0; r < 8; ++r) {
        float4 xv = *(const float4*)(&xs[r][k]);  // wave-uniform LDS broadcast
        acc[r] = fmaf(xv.x, w0, fmaf(xv.y, w1, fmaf(xv.z, w2, fmaf(xv.w, w3, acc[r]))));
      }
    }

    // frag-linear store: unit=(head, chunk=i0>>5, nt); elem(lane', t=r)
    {
      const int head = c >> 6, nt = (c >> 4) & 3, m15 = c & 15;
      const int unit = (head * 128 + (i0 >> 5)) * 4 + nt;
      const int lanep = ((i0 & 31) >> 3) * 16 + m15;
      f16x8 v;
#pragma unroll
      for (int r = 0; r < 8; ++r) v[r] = (_Float16)acc[r];
      *(f16x8*)(hb + (size_t)unit * 512 + lanep * 8) = v;
    }

    // per-block column sums (plain store, no atomics) for empty-row fallback
    {
      float loc = 0.f;
#pragma unroll
      for (int r = 0; r < 8; ++r) loc += acc[r];
      hsum_part[(size_t)blk * HD + c] = loc;
    }

    const int hw = c >> 6, lane = c & 63;
    const float as = a_src[lane], ad = a_dst[lane];
#pragma unroll
    for (int r = 0; r < 8; ++r) {
      float vs = acc[r] * as, vd = acc[r] * ad;
#pragma unroll
      for (int off = 1; off < 64; off <<= 1) {
        vs += __shfl_xor(vs, off);
        vd += __shfl_xor(vd, off);
      }
      if (lane == 0) {
        s_src[(size_t)(i0 + r) * HEADS + hw] = vs * LOG2E;
        s_dst_t[(size_t)hw * N + (i0 + r)] = vd * LOG2E;
      }
    }
  }
}

// ---------------- D2: MFMA aggregation + in-block LDS reduce + normalize ----
// block = 64 rows x 1 head; 16 waves = 2 row-groups (mg) x 8 j-slices (js).
// mg-pair waves of the same js read identical hb/sjb -> L1-shared.
// grid: head = blockIdx>>6 (rb inner); 64 === 0 mod 8 so all 4 head-blocks of
// the same rows land on the same XCD -> bits_t row-slice fetched once per XCD.
__global__ __launch_bounds__(1024, 4) void gat_fused(const _Float16* __restrict__ hb,
                                                     const float* __restrict__ s_src,
                                                     const float* __restrict__ s_dst_t,
                                                     const unsigned* __restrict__ bits_t,
                                                     const float* __restrict__ hsum_part,
                                                     float4* __restrict__ out) {
  __shared__ float red[8][64][68];  // 136 KB padded: 4-row stride=16 banks -> 2-way max
  __shared__ float lred[8][64];     // 2 KB

  const int tid = threadIdx.x;
  const int wv = tid >> 6;
  const int js = wv & 7;           // j-slice 0..7
  const int mg = wv >> 3;          // row-group 0..1
  const int lane = tid & 63;
  const int m15 = lane & 15;
  const int quad = lane >> 4;
  const int head = blockIdx.x >> 6;
  const int rb = blockIdx.x & 63;
  const int i0 = rb * 64 + mg * 32;
  const int rA = i0 + m15;
  const int rB = rA + 16;

  const float siA = s_src[(size_t)rA * HEADS + head];
  const float siB = s_src[(size_t)rB * HEADS + head];
  // exp2(lrelu(v)-8) = exp2(max(v-8, 0.2v-8)); hoist the si parts.
  const float siAa = siA - PSHIFT, siAb = 0.2f * siA - PSHIFT;
  const float siBa = siB - PSHIFT, siBb = 0.2f * siB - PSHIFT;

  // bits_t[row>>6][jc][row&63]; rows i0..i0+31 -> row>>6 = rb const.
  const unsigned* mt = bits_t + ((size_t)rb * 128 + js * 16) * 64 + mg * 32 + m15;
  const float* sjb = s_dst_t + (size_t)head * N + js * 512 + quad * 8;
  const _Float16* hbp = hb + ((size_t)(head * 128 + js * 16) * 4) * 512 + lane * 8;

  f32x4 accA0 = {0.f, 0.f, 0.f, 0.f}, accA1 = accA0, accA2 = accA0, accA3 = accA0;
  f32x4 accB0 = accA0, accB1 = accA0, accB2 = accA0, accB3 = accA0;
  f32x4 accLA = accA0, accLB = accA0;  // row-sums via ones-MFMA

  f16x8 onesv;
#pragma unroll
  for (int t = 0; t < 8; ++t) onesv[t] = (_Float16)1.0f;

  const int shq = quad * 8;

  for (int c = 0; c < 16; ++c) {
    const unsigned mwA = mt[c * 64];
    const unsigned mwB = mt[c * 64 + 16];
    const float4 sa = *(const float4*)(sjb + c * 32);
    const float4 sb = *(const float4*)(sjb + c * 32 + 4);

    const f16x8 b0 = *(const f16x8*)(hbp + (size_t)(c * 4 + 0) * 512);
    const f16x8 b1 = *(const f16x8*)(hbp + (size_t)(c * 4 + 1) * 512);
    const f16x8 b2 = *(const f16x8*)(hbp + (size_t)(c * 4 + 2) * 512);
    const f16x8 b3 = *(const f16x8*)(hbp + (size_t)(c * 4 + 3) * 512);

    const unsigned wA = mwA >> shq;
    const unsigned wB = mwB >> shq;
    const float sjs[8] = {sa.x, sa.y, sa.z, sa.w, sb.x, sb.y, sb.z, sb.w};

    F16x8u uA, uB;
#pragma unroll
    for (int t2 = 0; t2 < 4; ++t2) {
      float pA[2], pB[2];
#pragma unroll
      for (int q = 0; q < 2; ++q) {
        const int t = t2 * 2 + q;
        const float sj = sjs[t];
        const float mA = fmaxf(siAa + sj, fmaf(0.2f, sj, siAb));
        const float mB = fmaxf(siBa + sj, fmaf(0.2f, sj, siBb));
        const float xA = (((wA >> t) & 1u) ? mA : -1.0e38f);
        const float xB = (((wB >> t) & 1u) ? mB : -1.0e38f);
        pA[q] = __builtin_amdgcn_exp2f(xA);
        pB[q] = __builtin_amdgcn_exp2f(xB);
      }
      uA.h2[t2] = __builtin_amdgcn_cvt_pkrtz(pA[0], pA[1]);
      uB.h2[t2] = __builtin_amdgcn_cvt_pkrtz(pB[0], pB[1]);
    }

    accLA = __builtin_amdgcn_mfma_f32_16x16x32_f16(uA.v, onesv, accLA, 0, 0, 0);
    accLB = __builtin_amdgcn_mfma_f32_16x16x32_f16(uB.v, onesv, accLB, 0, 0, 0);
    accA0 = __builtin_amdgcn_mfma_f32_16x16x32_f16(uA.v, b0, accA0, 0, 0, 0);
    accA1 = __builtin_amdgcn_mfma_f32_16x16x32_f16(uA.v, b1, accA1, 0, 0, 0);
    accA2 = __builtin_amdgcn_mfma_f32_16x16x32_f16(uA.v, b2, accA2, 0, 0, 0);
    accA3 = __builtin_amdgcn_mfma_f32_16x16x32_f16(uA.v, b3, accA3, 0, 0, 0);
    accB0 = __builtin_amdgcn_mfma_f32_16x16x32_f16(uB.v, b0, accB0, 0, 0, 0);
    accB1 = __builtin_amdgcn_mfma_f32_16x16x32_f16(uB.v, b1, accB1, 0, 0, 0);
    accB2 = __builtin_amdgcn_mfma_f32_16x16x32_f16(uB.v, b2, accB2, 0, 0, 0);
    accB3 = __builtin_amdgcn_mfma_f32_16x16x32_f16(uB.v, b3, accB3, 0, 0, 0);
  }

  // row-sums: accL D-layout row = quad*4+reg, col = m15 (all cols equal)
  if (m15 == 0) {
#pragma unroll
    for (int reg = 0; reg < 4; ++reg) {
      lred[js][mg * 32 + quad * 4 + reg] = accLA[reg];
      lred[js][mg * 32 + 16 + quad * 4 + reg] = accLB[reg];
    }
  }

  // stash per-wave partial tiles: row = mg*32 + quad*4+reg (+16 for B), col = m15+16u
#pragma unroll
  for (int reg = 0; reg < 4; ++reg) {
    const int ra = mg * 32 + quad * 4 + reg;
    red[js][ra][m15 +  0] = accA0[reg];
    red[js][ra][m15 + 16] = accA1[reg];
    red[js][ra][m15 + 32] = accA2[reg];
    red[js][ra][m15 + 48] = accA3[reg];
    red[js][16 + ra][m15 +  0] = accB0[reg];
    red[js][16 + ra][m15 + 16] = accB1[reg];
    red[js][16 + ra][m15 + 32] = accB2[reg];
    red[js][16 + ra][m15 + 48] = accB3[reg];
  }
  __syncthreads();

  // combine 8 j-slices + normalize + write out. 1024 thr = 64 rows x 16 col4.
  const int row = tid >> 4;
  const int c4 = tid & 15;
  float4 o = {0.f, 0.f, 0.f, 0.f};
  float lt = 0.f;
#pragma unroll
  for (int k = 0; k < 8; ++k) {
    const float4 v = *(const float4*)&red[k][row][c4 * 4];
    o.x += v.x; o.y += v.y; o.z += v.z; o.w += v.w;
    lt += lred[k][row];
  }
  if (lt == 0.f) {
    // empty row -> exact uniform 1/N: sum h over all j (512 block slices)
    float4 hs = {0.f, 0.f, 0.f, 0.f};
    for (int b = 0; b < 512; ++b) {
      float4 t4 = ((const float4*)hsum_part)[(size_t)b * 64 + head * 16 + c4];
      hs.x += t4.x; hs.y += t4.y; hs.z += t4.z; hs.w += t4.w;
    }
    const float cst = 1.0f / (float)N;
    o.x = hs.x * cst; o.y = hs.y * cst; o.z = hs.z * cst; o.w = hs.w * cst;
  } else {
    const float inv = 1.0f / lt;
    o.x *= inv; o.y *= inv; o.z *= inv; o.w *= inv;
  }
  out[(size_t)(rb * 64 + row) * 64 + head * 16 + c4] = o;
}

extern "C" void kernel_launch(void* const* d_in, const int* in_sizes, int n_in,
                              void* d_out, int out_size, void* d_ws, size_t ws_size,
                              hipStream_t stream) {
  (void)in_sizes; (void)n_in; (void)out_size; (void)ws_size;
  const float* x = (const float*)d_in[0];
  const void* mask = d_in[1];
  const float* W = (const float*)d_in[2];
  const float* a_src = (const float*)d_in[3];
  const float* a_dst = (const float*)d_in[4];
  float* out = (float*)d_out;

  char* ws = (char*)d_ws;
  _Float16* hb = (_Float16*)(ws + WS_HB_OFF);
  float* s_src = (float*)(ws + WS_SSRC_OFF);
  float* s_dst_t = (float*)(ws + WS_SDT_OFF);
  unsigned* bits_t = (unsigned*)(ws + WS_BITT_OFF);
  float* hsum_part = (float*)(ws + WS_HSUMP_OFF);

  prep_k<<<2048 + N / 8, 256, 0, stream>>>(mask, bits_t, x, W, a_src, a_dst,
                                           hb, s_src, s_dst_t, hsum_part);
  gat_fused<<<256, 1024, 0, stream>>>(hb, s_src, s_dst_t, bits_t, hsum_part,
                                      (float4*)out);
}